// Round 4
// baseline (240.708 us; speedup 1.0000x reference)
//
#include <hip/hip_runtime.h>
#include <hip/hip_bf16.h>

// Problem constants (fixed by setup_inputs)
#define B   8
#define T   2048
#define C   256      // channels; 64 float4
#define L   32       // query rows / label count
#define DQ  512
#define NW  2017     // T - window_size + 1
#define NK  8        // num_chunks
#define CIC 4        // window/num_chunks
#define WT  32       // w-tile per block in fused kernel
#define SROWS (WT + (NK-1)*CIC)   // 60 S4 rows per tile
#define RROWS (WT - 1 + 32)       // 63 raw vis rows per tile

// ---------------- Kernel 1: enc1/enc2 = query @ W{1,2} + b{1,2} ----------------
// grid (8 lgroups, 8 b), block (256 c, 4 d-quarters). LDS reduce over quarters.
__global__ __launch_bounds__(1024) void enc_kernel(
    const float* __restrict__ query, const float* __restrict__ W1,
    const float* __restrict__ b1, const float* __restrict__ W2,
    const float* __restrict__ b2, float* __restrict__ enc1,
    float* __restrict__ enc2) {
  const int b = blockIdx.y, lg = blockIdx.x;   // 4 l per block
  const int c = threadIdx.x;                   // 0..255
  const int q = threadIdx.y;                   // 0..3 d-quarter
  __shared__ float qs[4 * DQ];                 // 8 KB
  __shared__ float red[2][4][4][256];          // [enc][q][j][c] 32 KB
  const float* qbase = query + ((size_t)b * L + lg * 4) * DQ;
  for (int i = q * 256 + c; i < 4 * DQ; i += 1024) qs[i] = qbase[i];
  __syncthreads();
  float a1[4] = {0.f, 0.f, 0.f, 0.f};
  float a2[4] = {0.f, 0.f, 0.f, 0.f};
  const int d0 = q * (DQ / 4);
#pragma unroll 4
  for (int dd = 0; dd < DQ / 4; ++dd) {
    const int d = d0 + dd;
    const float w1 = W1[d * C + c];
    const float w2 = W2[d * C + c];
#pragma unroll
    for (int j = 0; j < 4; ++j) {
      a1[j] = fmaf(qs[j * DQ + d], w1, a1[j]);
      a2[j] = fmaf(qs[j * DQ + d], w2, a2[j]);
    }
  }
#pragma unroll
  for (int j = 0; j < 4; ++j) {
    red[0][q][j][c] = a1[j];
    red[1][q][j][c] = a2[j];
  }
  __syncthreads();
  for (int o = q * 256 + c; o < 2048; o += 1024) {
    const int e = o >> 10;         // 0..1 (enc1/enc2)
    const int j = (o >> 8) & 3;    // row within lgroup
    const int cc = o & 255;
    const float v = red[e][0][j][cc] + red[e][1][j][cc] +
                    red[e][2][j][cc] + red[e][3][j][cc];
    const size_t off = ((size_t)b * L + lg * 4 + j) * C + cc;
    if (e == 0) enc1[off] = v + b1[cc];
    else        enc2[off] = v + b2[cc];
  }
}

// ------ Kernel 2 (fused): labels + majority vote + S4 means + modulated output ------
// grid (ceil(NW/WT)=64, 8 b), block 256. Reads each vis row ONCE (coalesced),
// everything else served from LDS. LDS ~96 KB -> 1 block/CU.
__global__ __launch_bounds__(256) void fused_kernel(
    const float* __restrict__ vis, const float* __restrict__ enc1,
    const float* __restrict__ enc2, float* __restrict__ out) {
  const int b = blockIdx.y;
  const int w0 = blockIdx.x * WT;
  const int tid = threadIdx.x;

  __shared__ float4 raw[RROWS * (C / 4)];   // 63 KB; rows 0..59 become S4 in place
  __shared__ float pacc[4][RROWS][33];      // 33.3 KB; +1 pad -> conflict-free
  __shared__ int tlabel[RROWS];
  __shared__ int slbl[SROWS];

  // --- e1 register fragment for the sim phase: thread = (l, part) ---
  const int l = tid & 31;     // label row
  const int part = tid >> 5;  // 8-way channel split (32 floats each)
  float4 ef[8];
  {
    const float4* e1p = (const float4*)(enc1 + ((size_t)b * L + l) * C) + part * 8;
#pragma unroll
    for (int j = 0; j < 8; ++j) ef[j] = e1p[j];   // L2-hot, issued early
  }

  // --- Phase 1: stage raw vis rows w0..w0+62 coalesced into LDS ---
  const float4* vb = (const float4*)(vis + (size_t)b * T * C);
  for (int i = tid; i < RROWS * (C / 4); i += 256) {
    int row = w0 + (i >> 6);
    row = row > (T - 1) ? (T - 1) : row;   // clamp; clamped rows never used
    raw[i] = vb[(size_t)row * (C / 4) + (i & 63)];
  }
  __syncthreads();

  // --- Phase 2: sim partials. raw reads are 2-address LDS broadcasts (free). ---
  for (int t = 0; t < RROWS; ++t) {
    const float4* vr = &raw[t * (C / 4) + part * 8];
    float a = 0.f;
#pragma unroll
    for (int j = 0; j < 8; ++j) {
      const float4 v = vr[j];
      a = fmaf(v.x, ef[j].x, fmaf(v.y, ef[j].y, fmaf(v.z, ef[j].z, fmaf(v.w, ef[j].w, a))));
    }
    a += __shfl_down(a, 32);                    // combine part pairs (deterministic)
    if (!(tid & 32)) pacc[tid >> 6][t][l] = a;  // wave-id slot; banks (t+l)%32 distinct
  }
  __syncthreads();

  // --- Phase 3: argmax over l (first max wins, matches jnp.argmax) ---
  if (tid < RROWS) {
    float bv = -INFINITY;
    int bi = 0;
#pragma unroll
    for (int ll = 0; ll < L; ++ll) {
      const float s = pacc[0][tid][ll] + pacc[1][tid][ll] +
                      pacc[2][tid][ll] + pacc[3][tid][ll];
      if (s > bv) { bv = s; bi = ll; }
    }
    tlabel[tid] = bi;
  }
  __syncthreads();

  // --- Phase 4a: majority vote (tie -> smallest label == argmax of counts) ---
  if (tid < SROWS) {
    const int l0 = tlabel[tid], l1 = tlabel[tid + 1];
    const int l2 = tlabel[tid + 2], l3 = tlabel[tid + 3];
    const int c0 = 1 + (l0 == l1) + (l0 == l2) + (l0 == l3);
    const int c1 = 1 + (l1 == l0) + (l1 == l2) + (l1 == l3);
    const int c2 = 1 + (l2 == l0) + (l2 == l1) + (l2 == l3);
    const int c3 = 1 + (l3 == l0) + (l3 == l1) + (l3 == l2);
    int best = l0, bc = c0;
    if (c1 > bc || (c1 == bc && l1 < best)) { best = l1; bc = c1; }
    if (c2 > bc || (c2 == bc && l2 < best)) { best = l2; bc = c2; }
    if (c3 > bc || (c3 == bc && l3 < best)) { best = l3; bc = c3; }
    slbl[tid] = best;
  }

  // --- Phase 4b: load this wave's 18 raw rows to registers (lane=c4 remap) ---
  const int lane = tid & 63;
  const int wv = tid >> 6;
  float4 r[18];
  {
    const int s0 = wv * (SROWS / 4);
#pragma unroll
    for (int j = 0; j < 18; ++j) r[j] = raw[(s0 + j) * (C / 4) + lane];
  }
  __syncthreads();   // all raw reads complete before in-place overwrite

  // --- Phase 5: S4[s] = mean4 written in place over raw row s ---
  {
    const int s0 = wv * (SROWS / 4);
#pragma unroll
    for (int s = 0; s < SROWS / 4; ++s) {
      float4 o;
      o.x = (r[s].x + r[s + 1].x + r[s + 2].x + r[s + 3].x) * 0.25f;
      o.y = (r[s].y + r[s + 1].y + r[s + 2].y + r[s + 3].y) * 0.25f;
      o.z = (r[s].z + r[s + 1].z + r[s + 2].z + r[s + 3].z) * 0.25f;
      o.w = (r[s].w + r[s + 1].w + r[s + 2].w + r[s + 3].w) * 0.25f;
      raw[(s0 + s) * (C / 4) + lane] = o;
    }
  }
  __syncthreads();

  // --- Phase 6: output. wave wv owns k in {wv, wv+4}; fully coalesced stores ---
  const float4* e2b = (const float4*)(enc2 + (size_t)b * L * C);
  float4* outp = (float4*)out;
  const int wlim = (NW - w0) < WT ? (NW - w0) : WT;
#pragma unroll
  for (int kk = 0; kk < 2; ++kk) {
    const int k = wv + kk * 4;
#pragma unroll 4
    for (int w = 0; w < wlim; ++w) {
      const int s = w + CIC * k;
      const int lb = slbl[s];                       // LDS broadcast
      const float4 e = e2b[lb * (C / 4) + lane];    // L2-hot
      const float4 sv = raw[s * (C / 4) + lane];    // S4 (in-place)
      float4 o;
      o.x = e.x * sv.x; o.y = e.y * sv.y; o.z = e.z * sv.z; o.w = e.w * sv.w;
      outp[(((size_t)b * NW + w0 + w) * NK + k) * (C / 4) + lane] = o;
    }
  }
}

extern "C" void kernel_launch(void* const* d_in, const int* in_sizes, int n_in,
                              void* d_out, int out_size, void* d_ws, size_t ws_size,
                              hipStream_t stream) {
  const float* vis   = (const float*)d_in[0];
  const float* query = (const float*)d_in[1];
  const float* W1    = (const float*)d_in[2];
  const float* b1    = (const float*)d_in[3];
  const float* W2    = (const float*)d_in[4];
  const float* b2    = (const float*)d_in[5];
  float* out = (float*)d_out;

  // Workspace: enc1 (64K f), enc2 (64K f) = 512 KB
  float* enc1 = (float*)d_ws;
  float* enc2 = enc1 + (size_t)B * L * C;

  enc_kernel<<<dim3(L / 4, B), dim3(256, 4), 0, stream>>>(query, W1, b1, W2, b2, enc1, enc2);
  fused_kernel<<<dim3((NW + WT - 1) / WT, B), 256, 0, stream>>>(vis, enc1, enc2, out);
}

// Round 5
// 213.406 us; speedup vs baseline: 1.1279x; 1.1279x over previous
//
#include <hip/hip_runtime.h>
#include <hip/hip_bf16.h>

// Problem constants (fixed by setup_inputs)
#define B   8
#define T   2048
#define C   256      // channels; 64 float4
#define L   32       // query rows / label count
#define DQ  512
#define NW  2017     // T - window_size + 1
#define NK  8        // num_chunks
#define CIC 4        // window/num_chunks
#define WT  32       // w-tile per block in out kernel
#define SROWS (WT + (NK-1)*CIC)   // 60 S4 rows per tile
#define LT  32       // t-rows per label block

// ---------------- Kernel 1: enc1/enc2 = query @ W{1,2} + b{1,2} ----------------
__global__ __launch_bounds__(1024) void enc_kernel(
    const float* __restrict__ query, const float* __restrict__ W1,
    const float* __restrict__ b1, const float* __restrict__ W2,
    const float* __restrict__ b2, float* __restrict__ enc1,
    float* __restrict__ enc2) {
  const int b = blockIdx.y, lg = blockIdx.x;   // 4 l per block
  const int c = threadIdx.x;                   // 0..255
  const int q = threadIdx.y;                   // 0..3 d-quarter
  __shared__ float qs[4 * DQ];                 // 8 KB
  __shared__ float red[2][4][4][256];          // [enc][q][j][c] 32 KB
  const float* qbase = query + ((size_t)b * L + lg * 4) * DQ;
  for (int i = q * 256 + c; i < 4 * DQ; i += 1024) qs[i] = qbase[i];
  __syncthreads();
  float a1[4] = {0.f, 0.f, 0.f, 0.f};
  float a2[4] = {0.f, 0.f, 0.f, 0.f};
  const int d0 = q * (DQ / 4);
#pragma unroll 4
  for (int dd = 0; dd < DQ / 4; ++dd) {
    const int d = d0 + dd;
    const float w1 = W1[d * C + c];
    const float w2 = W2[d * C + c];
#pragma unroll
    for (int j = 0; j < 4; ++j) {
      a1[j] = fmaf(qs[j * DQ + d], w1, a1[j]);
      a2[j] = fmaf(qs[j * DQ + d], w2, a2[j]);
    }
  }
#pragma unroll
  for (int j = 0; j < 4; ++j) {
    red[0][q][j][c] = a1[j];
    red[1][q][j][c] = a2[j];
  }
  __syncthreads();
  for (int o = q * 256 + c; o < 2048; o += 1024) {
    const int e = o >> 10;
    const int j = (o >> 8) & 3;
    const int cc = o & 255;
    const float v = red[e][0][j][cc] + red[e][1][j][cc] +
                    red[e][2][j][cc] + red[e][3][j][cc];
    const size_t off = ((size_t)b * L + lg * 4 + j) * C + cc;
    if (e == 0) enc1[off] = v + b1[cc];
    else        enc2[off] = v + b2[cc];
  }
}

// ---------------- Kernel 2: clip_labels = argmax_l (vis . enc1) ----------------
// grid (T/32=64, 8 b), block 256. Stage 32 rows coalesced -> LDS; sim with
// enc1 fragments in registers (LDS raw reads are 2-address broadcasts = free).
// LDS ~51 KB -> 3 blocks/CU, 12 waves/CU.
__global__ __launch_bounds__(256) void label_kernel(
    const float* __restrict__ vis, const float* __restrict__ enc1,
    int* __restrict__ labels) {
  const int b = blockIdx.y;
  const int t0 = blockIdx.x * LT;
  const int tid = threadIdx.x;
  const int l = tid & 31;     // label row
  const int part = tid >> 5;  // 8-way channel split (32 ch each)
  __shared__ float4 raw[LT * (C / 4)];               // 32 KB
  __shared__ alignas(16) float pacc[4][LT][36];      // 18.4 KB; 36: 16B-aligned rows

  float4 ef[8];
  {
    const float4* e1p = (const float4*)(enc1 + ((size_t)b * L + l) * C) + part * 8;
#pragma unroll
    for (int j = 0; j < 8; ++j) ef[j] = e1p[j];   // L2-hot
  }
  const float4* vb = (const float4*)(vis + (size_t)b * T * C);
  for (int i = tid; i < LT * (C / 4); i += 256)
    raw[i] = vb[(size_t)(t0 + (i >> 6)) * (C / 4) + (i & 63)];
  __syncthreads();

  for (int t = 0; t < LT; ++t) {
    const float4* vr = &raw[t * (C / 4) + part * 8];
    float a = 0.f;
#pragma unroll
    for (int j = 0; j < 8; ++j) {
      const float4 v = vr[j];
      a = fmaf(v.x, ef[j].x, fmaf(v.y, ef[j].y, fmaf(v.z, ef[j].z, fmaf(v.w, ef[j].w, a))));
    }
    a += __shfl_down(a, 32);                    // part pair sum (deterministic)
    if (!(tid & 32)) pacc[tid >> 6][t][l] = a;  // banks (4t+l)%32 distinct: free
  }
  __syncthreads();

  // argmax over l, first max wins (matches jnp.argmax); sum order == R4 fused
  if (tid < LT) {
    float4 s4[8];
#pragma unroll
    for (int j = 0; j < 8; ++j) s4[j] = make_float4(0.f, 0.f, 0.f, 0.f);
#pragma unroll
    for (int p = 0; p < 4; ++p) {
      const float4* pp = (const float4*)pacc[p][tid];
#pragma unroll
      for (int j = 0; j < 8; ++j) {
        s4[j].x += pp[j].x; s4[j].y += pp[j].y;
        s4[j].z += pp[j].z; s4[j].w += pp[j].w;
      }
    }
    float bv = -INFINITY;
    int bi = 0;
#pragma unroll
    for (int j = 0; j < 8; ++j) {
      if (s4[j].x > bv) { bv = s4[j].x; bi = 4 * j; }
      if (s4[j].y > bv) { bv = s4[j].y; bi = 4 * j + 1; }
      if (s4[j].z > bv) { bv = s4[j].z; bi = 4 * j + 2; }
      if (s4[j].w > bv) { bv = s4[j].w; bi = 4 * j + 3; }
    }
    labels[(size_t)b * T + t0 + tid] = bi;
  }
}

// ---------------- Kernel 3: majority vote + S4 means + modulated output ----------------
// grid (ceil(NW/WT)=64, 8 b), block 256. LDS 60 KB -> 2 blocks/CU.
__global__ __launch_bounds__(256) void out_kernel(
    const float* __restrict__ vis, const float* __restrict__ enc2,
    const int* __restrict__ labels, float* __restrict__ out) {
  const int b = blockIdx.y;
  const int w0 = blockIdx.x * WT;
  const int tid = threadIdx.x;
  const int lane = tid & 63;
  const int wv = tid >> 6;              // wave id, wave-uniform
  __shared__ float4 S4[SROWS * (C / 4)];  // 60 KB, pre-scaled by 0.25
  __shared__ int slbl[SROWS];

  // Prefetch this thread's 4 vote labels (in flight alongside raw loads)
  int l0 = 0, l1 = 0, l2 = 0, l3 = 0;
  if (tid < SROWS) {
    const int* lb = labels + (size_t)b * T;
    const int t = w0 + tid;
#define LCL(tt) lb[(tt) > (T - 1) ? (T - 1) : (tt)]
    l0 = LCL(t); l1 = LCL(t + 1); l2 = LCL(t + 2); l3 = LCL(t + 3);
#undef LCL
  }

  // Phase 1: 18 independent raw-row loads per wave (one vmcnt drain)
  const float4* vb = (const float4*)(vis + (size_t)b * T * C);
  float4 r[18];
  {
    const int s0 = wv * (SROWS / 4);
#pragma unroll
    for (int j = 0; j < 18; ++j) {
      int t = w0 + s0 + j;
      t = t > (T - 1) ? (T - 1) : t;    // clamp; clamped rows never used
      r[j] = vb[(size_t)t * (C / 4) + lane];
    }
  }

  // Phase 2: majority vote (tie -> smallest label == argmax of one-hot counts)
  if (tid < SROWS) {
    const int c0 = 1 + (l0 == l1) + (l0 == l2) + (l0 == l3);
    const int c1 = 1 + (l1 == l0) + (l1 == l2) + (l1 == l3);
    const int c2 = 1 + (l2 == l0) + (l2 == l1) + (l2 == l3);
    const int c3 = 1 + (l3 == l0) + (l3 == l1) + (l3 == l2);
    int best = l0, bc = c0;
    if (c1 > bc || (c1 == bc && l1 < best)) { best = l1; bc = c1; }
    if (c2 > bc || (c2 == bc && l2 < best)) { best = l2; bc = c2; }
    if (c3 > bc || (c3 == bc && l3 < best)) { best = l3; bc = c3; }
    slbl[tid] = best;
  }

  // Phase 3: S4[s] = mean4(raw rows s..s+3), 15 rows per wave
  {
    const int s0 = wv * (SROWS / 4);
#pragma unroll
    for (int s = 0; s < SROWS / 4; ++s) {
      float4 o;
      o.x = (r[s].x + r[s + 1].x + r[s + 2].x + r[s + 3].x) * 0.25f;
      o.y = (r[s].y + r[s + 1].y + r[s + 2].y + r[s + 3].y) * 0.25f;
      o.z = (r[s].z + r[s + 1].z + r[s + 2].z + r[s + 3].z) * 0.25f;
      o.w = (r[s].w + r[s + 1].w + r[s + 2].w + r[s + 3].w) * 0.25f;
      S4[(s0 + s) * (C / 4) + lane] = o;
    }
  }
  __syncthreads();

  // Phase 4: output. wave wv owns k in {wv, wv+4}; fully coalesced 1KB stores
  const float4* e2b = (const float4*)(enc2 + (size_t)b * L * C);
  float4* outp = (float4*)out;
  const int wlim = (NW - w0) < WT ? (NW - w0) : WT;
#pragma unroll
  for (int kk = 0; kk < 2; ++kk) {
    const int k = wv + kk * 4;
#pragma unroll 4
    for (int w = 0; w < wlim; ++w) {
      const int s = w + CIC * k;
      const int lb = slbl[s];                       // LDS broadcast
      const float4 e = e2b[lb * (C / 4) + lane];    // L1/L2-hot (32 KB set)
      const float4 sv = S4[s * (C / 4) + lane];
      float4 o;
      o.x = e.x * sv.x; o.y = e.y * sv.y; o.z = e.z * sv.z; o.w = e.w * sv.w;
      outp[(((size_t)b * NW + w0 + w) * NK + k) * (C / 4) + lane] = o;
    }
  }
}

extern "C" void kernel_launch(void* const* d_in, const int* in_sizes, int n_in,
                              void* d_out, int out_size, void* d_ws, size_t ws_size,
                              hipStream_t stream) {
  const float* vis   = (const float*)d_in[0];
  const float* query = (const float*)d_in[1];
  const float* W1    = (const float*)d_in[2];
  const float* b1    = (const float*)d_in[3];
  const float* W2    = (const float*)d_in[4];
  const float* b2    = (const float*)d_in[5];
  float* out = (float*)d_out;

  // Workspace: enc1 (64K f), enc2 (64K f), labels (16K int) = 576 KB
  float* enc1 = (float*)d_ws;
  float* enc2 = enc1 + (size_t)B * L * C;
  int* labels = (int*)(enc2 + (size_t)B * L * C);

  enc_kernel<<<dim3(L / 4, B), dim3(256, 4), 0, stream>>>(query, W1, b1, W2, b2, enc1, enc2);
  label_kernel<<<dim3(T / LT, B), 256, 0, stream>>>(vis, enc1, labels);
  out_kernel<<<dim3((NW + WT - 1) / WT, B), 256, 0, stream>>>(vis, enc2, labels, out);
}